// Round 1
// baseline (58389.252 us; speedup 1.0000x reference)
//
#include <hip/hip_runtime.h>

// 2-layer tanh RNN, B=64, S=2048, D=HID=512, fp32.
// One persistent cooperative kernel; pipelined layers (layer1 lags 1 step);
// one custom grid barrier per macro-step (S+1 = 2049 barriers).
//
// Grid: 256 blocks x 256 threads (1 block/CU).
//   blocks 0..127   -> layer 0, tiles: 4 b-groups(16) x 32 j-groups(16)
//   blocks 128..255 -> layer 1, same tiling
// Thread (c = tid>>4, j = tid&15): owns 64-k chunk of column j_glob's
//   concatenated weights [W_ih | W_hh] in 64 VGPRs (loaded once),
//   computes partial dots for all 16 batch rows of its block.
// ws layout: [0,4096): barrier counters; [4096,...): h0[2], h1[2] buffers.

#define SEQ 2048

__global__ __launch_bounds__(256, 1)
void rnn_persist(const int* __restrict__ src, const float* __restrict__ embed,
                 const float* __restrict__ W_ih, const float* __restrict__ W_hh,
                 const float* __restrict__ b_ih, const float* __restrict__ b_hh,
                 float* __restrict__ out, float* ws_f, unsigned* bar)
{
    __shared__ float Xlds[16 * 1024];   // 64 KB: 16 rows x [x(512)|h(512)]
                                        // first 1 KB re-used as reduction buf

    const int tid   = threadIdx.x;
    const int bid   = blockIdx.x;
    const int layer = bid >> 7;         // 0 or 1
    const int lid   = bid & 127;
    const int bg    = lid >> 5;         // batch group 0..3 (16 rows each)
    const int jg    = lid & 31;         // column group 0..31 (16 cols each)
    const int c     = tid >> 4;         // k-chunk 0..15 (64 k's each); also output row
    const int j     = tid & 15;
    const int j_glob = jg * 16 + j;

    // ---- load this thread's weight chunk into registers (persistent) ----
    // k in [c*64, c*64+64): c<8 -> W_ih cols, c>=8 -> W_hh cols
    float4 wreg[16];
    {
        const float* wsrc = (c < 8)
            ? (W_ih + ((size_t)layer * 512 + j_glob) * 512 + c * 64)
            : (W_hh + ((size_t)layer * 512 + j_glob) * 512 + (c - 8) * 64);
        #pragma unroll
        for (int i = 0; i < 16; ++i) wreg[i] = ((const float4*)wsrc)[i];
    }
    const float bias = b_ih[layer * 512 + j_glob] + b_hh[layer * 512 + j_glob];

    float* h0buf[2] = { ws_f,          ws_f + 32768 };   // each 64*512 fp32
    float* h1buf[2] = { ws_f + 65536,  ws_f + 98304 };

    const int r      = c;               // staging row this thread fills
    const int s      = j;               // staging segment
    const int brow_r = bg * 16 + r;     // global batch row staged
    const int b_out  = bg * 16 + c;     // global batch row of owned output

    const int wv   = tid >> 6;          // wave 0..3
    const int lane = tid & 63;

    for (int m = 0; m <= SEQ; ++m) {
        const bool active = (layer == 0) ? (m < SEQ) : (m >= 1);
        const int  t      = (layer == 0) ? m : (m - 1);

        if (active) {
            // ---- stage Xcat = [x_t | h_prev] rows into LDS ----
            const float* baseA;  // k < 512 source
            const float* baseB;  // k >= 512 source
            if (layer == 0) {
                const int row = src[brow_r * SEQ + t];
                baseA = embed + (size_t)row * 512;
                baseB = h0buf[t & 1] + brow_r * 512;        // h0_{t-1}
            } else {
                baseA = h0buf[(t + 1) & 1] + brow_r * 512;  // h0_t (fresh)
                baseB = h1buf[t & 1] + brow_r * 512;        // h1_{t-1}
            }
            #pragma unroll
            for (int i = 0; i < 8; ++i) {
                float4 v = *(const float4*)(baseA + i * 64 + s * 4);
                *(float4*)&Xlds[r * 1024 + i * 64 + s * 4] = v;
            }
            #pragma unroll
            for (int i = 0; i < 8; ++i) {
                float4 v = *(const float4*)(baseB + i * 64 + s * 4);
                *(float4*)&Xlds[r * 1024 + 512 + i * 64 + s * 4] = v;
            }
            __syncthreads();

            // ---- partial dots: 16 batch rows x this thread's 64 k's ----
            float partial[16];
            #pragma unroll
            for (int b = 0; b < 16; ++b) {
                const float* xp = &Xlds[b * 1024 + c * 64];
                float ax = 0.f, ay = 0.f, az = 0.f, aw = 0.f;
                #pragma unroll
                for (int i = 0; i < 16; ++i) {
                    float4 x = ((const float4*)xp)[i];
                    ax += x.x * wreg[i].x; ay += x.y * wreg[i].y;
                    az += x.z * wreg[i].z; aw += x.w * wreg[i].w;
                }
                partial[b] = (ax + ay) + (az + aw);
            }
            // reduce over the 4 k-chunks living in this wave (lane bits 4,5)
            #pragma unroll
            for (int b = 0; b < 16; ++b) {
                partial[b] += __shfl_xor(partial[b], 16, 64);
                partial[b] += __shfl_xor(partial[b], 32, 64);
            }
            __syncthreads();            // all Xlds reads done -> safe to alias
            float* red = Xlds;          // [4 waves][16 b][16 j] = 4 KB
            if ((lane >> 4) == 0) {     // one lane set per (wave, j)
                #pragma unroll
                for (int b = 0; b < 16; ++b)
                    red[wv * 256 + b * 16 + lane] = partial[b];
            }
            __syncthreads();

            // ---- finalize output element (b_out, j_glob) ----
            float z = red[0 * 256 + c * 16 + j] + red[1 * 256 + c * 16 + j]
                    + red[2 * 256 + c * 16 + j] + red[3 * 256 + c * 16 + j]
                    + bias;
            float h = tanhf(z);
            float* hw = (layer == 0) ? h0buf[(t + 1) & 1] : h1buf[(t + 1) & 1];
            hw[b_out * 512 + j_glob] = h;
            if (t == SEQ - 1)
                out[layer * (64 * 512) + b_out * 512 + j_glob] = h;
        }

        // ---- grid barrier (two-level, monotonic generations) ----
        __syncthreads();
        if (tid == 0) {
            __threadfence();  // release writes to device scope
            const int g = bid & 7;
            unsigned old = __hip_atomic_fetch_add(&bar[g * 64], 1u,
                              __ATOMIC_RELAXED, __HIP_MEMORY_SCOPE_AGENT);
            if (old == (unsigned)(32 * (m + 1) - 1))   // last of my group
                __hip_atomic_fetch_add(&bar[512], 1u,
                              __ATOMIC_RELAXED, __HIP_MEMORY_SCOPE_AGENT);
            while (__hip_atomic_load(&bar[512], __ATOMIC_ACQUIRE,
                              __HIP_MEMORY_SCOPE_AGENT) < (unsigned)(8 * (m + 1)))
                __builtin_amdgcn_s_sleep(2);
        }
        __syncthreads();
    }
}

extern "C" void kernel_launch(void* const* d_in, const int* in_sizes, int n_in,
                              void* d_out, int out_size, void* d_ws, size_t ws_size,
                              hipStream_t stream) {
    const int*   src   = (const int*)  d_in[0];
    const float* embed = (const float*)d_in[1];
    const float* W_ih  = (const float*)d_in[2];
    const float* W_hh  = (const float*)d_in[3];
    const float* b_ih  = (const float*)d_in[4];
    const float* b_hh  = (const float*)d_in[5];
    float*    out  = (float*)d_out;
    unsigned* bar  = (unsigned*)d_ws;                    // [0, 4096)
    float*    ws_f = (float*)((char*)d_ws + 4096);       // 4 x 128 KB h buffers

    // ws is poisoned 0xAA before every timed launch: zero counters + h state
    hipMemsetAsync(d_ws, 0, 4096 + 4 * 64 * 512 * 4, stream);

    void* args[] = { (void*)&src, (void*)&embed, (void*)&W_ih, (void*)&W_hh,
                     (void*)&b_ih, (void*)&b_hh, (void*)&out, (void*)&ws_f,
                     (void*)&bar };
    hipLaunchCooperativeKernel((void*)rnn_persist, dim3(256), dim3(256),
                               args, 0, stream);
}

// Round 2
// 35535.208 us; speedup vs baseline: 1.6431x; 1.6431x over previous
//
#include <hip/hip_runtime.h>

// 2-layer tanh RNN, B=64, S=2048, D=HID=512.
// Persistent cooperative kernel, pipelined layers, per-batch-group barriers.
//
// Grid 256x256. Block (layer = bid>>7, bg = (bid&127)>>5, jg = bid&31):
// computes h tile [16 batch rows x 16 cols] each step via MFMA 16x16x32_f16.
// Each wave owns K-chunk of 256 (of Xcat = [x|h_prev], K=1024): 8 MFMAs,
// B-operand (weights, f16) persistent in 32 VGPRs. Cross-wave K-reduce in LDS.
// h state lives in global ws as f16; sync = 4 independent 64-block clusters
// (batch groups are fully independent), two-level monotonic barrier.

#define SEQ 2048
#define LDSTR 1032   // padded f16 row stride: 2064 B == 16 mod 128 -> 2-way banks

typedef _Float16 half8 __attribute__((ext_vector_type(8)));
typedef float floatx4 __attribute__((ext_vector_type(4)));

__device__ inline half8 cvt8(const float* p) {
    float4 f0 = ((const float4*)p)[0];
    float4 f1 = ((const float4*)p)[1];
    half8 h;
    h[0] = (_Float16)f0.x; h[1] = (_Float16)f0.y;
    h[2] = (_Float16)f0.z; h[3] = (_Float16)f0.w;
    h[4] = (_Float16)f1.x; h[5] = (_Float16)f1.y;
    h[6] = (_Float16)f1.z; h[7] = (_Float16)f1.w;
    return h;
}

__global__ __launch_bounds__(256, 1)
void rnn_persist(const int* __restrict__ src, const float* __restrict__ embed,
                 const float* __restrict__ W_ih, const float* __restrict__ W_hh,
                 const float* __restrict__ b_ih, const float* __restrict__ b_hh,
                 float* __restrict__ out, _Float16* hbase, unsigned* bar)
{
    __shared__ __align__(16) _Float16 Xlds[16 * LDSTR];  // 33 KB
    __shared__ __align__(16) float    red[4 * 256];      // 4 KB partial tiles

    const int tid   = threadIdx.x;
    const int bid   = blockIdx.x;
    const int layer = bid >> 7;
    const int lid   = bid & 127;
    const int bg    = lid >> 5;          // batch group (16 rows)
    const int jg    = lid & 31;          // column group (16 cols)

    const int lane = tid & 63;
    const int kw   = tid >> 6;           // wave id = K-chunk (256 wide)
    const int q    = lane >> 4;          // MFMA quad
    const int rr   = lane & 15;          // MFMA row (A) / col (B)

    // ---- persistent weights: B-frag B[k][n], n = jg*16+rr, f16, 32 VGPRs ----
    half8 bw[8];
    {
        const int wrow = jg * 16 + rr;   // output column = weight row
        const float* Wmat = (kw < 2)
            ? (W_ih + ((size_t)layer * 512 + wrow) * 512)
            : (W_hh + ((size_t)layer * 512 + wrow) * 512);
        const int kbase = (kw & 1) * 256 + q * 8;
        #pragma unroll
        for (int u = 0; u < 8; ++u)
            bw[u] = cvt8(Wmat + kbase + u * 32);
    }

    const int frow = tid >> 4;           // finalize/staging row (0..15)
    const int fcol = tid & 15;           // finalize col / staging chunk
    const float bias = b_ih[layer * 512 + jg * 16 + fcol]
                     + b_hh[layer * 512 + jg * 16 + fcol];

    _Float16* h0buf[2] = { hbase,         hbase + 32768 };  // 64x512 f16 each
    _Float16* h1buf[2] = { hbase + 65536, hbase + 98304 };

    const half8 hzero = { (_Float16)0, (_Float16)0, (_Float16)0, (_Float16)0,
                          (_Float16)0, (_Float16)0, (_Float16)0, (_Float16)0 };

    // ---- per-cluster (bg) two-level barrier: 8 groups x 8 members ----
    const int member   = layer * 32 + jg;                 // 0..63 in cluster
    const int gcnt_idx = (bg * 8 + (member >> 3)) * 64;   // 256-B spaced
    const int mast_idx = 2048 + bg * 64;

    const int brow = bg * 16 + frow;     // global batch row for this thread

    for (int m = 0; m <= SEQ; ++m) {
        const bool active = (layer == 0) ? (m < SEQ) : (m >= 1);
        const int  t      = (layer == 0) ? m : (m - 1);

        if (active) {
            // ---- stage Xcat row (f16) into LDS: 16 threads per row,
            //      interleaved 8-elem chunks {fcol, fcol+16, +32, +48} ----
            _Float16* dstrow = &Xlds[frow * LDSTR];
            if (layer == 0) {
                const int erow = src[brow * SEQ + t];
                const float* ebase = embed + (size_t)erow * 512;
                #pragma unroll
                for (int mm = 0; mm < 4; ++mm) {
                    const int ch = fcol + 16 * mm;
                    *(half8*)&dstrow[ch * 8] = cvt8(ebase + ch * 8);
                }
                if (t == 0) {
                    #pragma unroll
                    for (int mm = 0; mm < 4; ++mm)
                        *(half8*)&dstrow[512 + (fcol + 16 * mm) * 8] = hzero;
                } else {
                    const _Float16* hb = h0buf[t & 1] + brow * 512;
                    #pragma unroll
                    for (int mm = 0; mm < 4; ++mm) {
                        const int ch = fcol + 16 * mm;
                        *(half8*)&dstrow[512 + ch * 8] = *(const half8*)&hb[ch * 8];
                    }
                }
            } else {
                const _Float16* ha = h0buf[(t + 1) & 1] + brow * 512;  // h0_t
                #pragma unroll
                for (int mm = 0; mm < 4; ++mm) {
                    const int ch = fcol + 16 * mm;
                    *(half8*)&dstrow[ch * 8] = *(const half8*)&ha[ch * 8];
                }
                if (t == 0) {
                    #pragma unroll
                    for (int mm = 0; mm < 4; ++mm)
                        *(half8*)&dstrow[512 + (fcol + 16 * mm) * 8] = hzero;
                } else {
                    const _Float16* hb = h1buf[t & 1] + brow * 512;
                    #pragma unroll
                    for (int mm = 0; mm < 4; ++mm) {
                        const int ch = fcol + 16 * mm;
                        *(half8*)&dstrow[512 + ch * 8] = *(const half8*)&hb[ch * 8];
                    }
                }
            }
            __syncthreads();

            // ---- MFMA: A[m=rr][k] from LDS, B from registers, K=256/wave ----
            floatx4 acc = { 0.f, 0.f, 0.f, 0.f };
            const _Float16* arow = &Xlds[rr * LDSTR + kw * 256 + q * 8];
            #pragma unroll
            for (int u = 0; u < 8; ++u) {
                half8 a = *(const half8*)&arow[u * 32];
                acc = __builtin_amdgcn_mfma_f32_16x16x32_f16(a, bw[u], acc, 0, 0, 0);
            }
            // partial tile -> LDS: red[kw][row=q*4+reg][col=rr]
            #pragma unroll
            for (int reg = 0; reg < 4; ++reg)
                red[kw * 256 + (q * 4 + reg) * 16 + rr] = acc[reg];
            __syncthreads();

            // ---- finalize element (frow, fcol): K-reduce + bias + tanh ----
            float z = red[tid] + red[256 + tid] + red[512 + tid] + red[768 + tid]
                    + bias;
            float h = tanhf(z);
            const int jcol = jg * 16 + fcol;
            _Float16* hw = (layer == 0) ? h0buf[(t + 1) & 1] : h1buf[(t + 1) & 1];
            hw[brow * 512 + jcol] = (_Float16)h;
            if (t == SEQ - 1)
                out[layer * (64 * 512) + brow * 512 + jcol] = h;
        }

        // ---- cluster barrier (monotonic generations) ----
        __syncthreads();
        if (tid == 0) {
            __threadfence();
            unsigned old = __hip_atomic_fetch_add(&bar[gcnt_idx], 1u,
                              __ATOMIC_RELAXED, __HIP_MEMORY_SCOPE_AGENT);
            if (old == (unsigned)(8 * (m + 1) - 1))
                __hip_atomic_fetch_add(&bar[mast_idx], 1u,
                              __ATOMIC_RELAXED, __HIP_MEMORY_SCOPE_AGENT);
            while (__hip_atomic_load(&bar[mast_idx], __ATOMIC_ACQUIRE,
                              __HIP_MEMORY_SCOPE_AGENT) < (unsigned)(8 * (m + 1)))
                __builtin_amdgcn_s_sleep(1);
        }
        __syncthreads();
    }
}

extern "C" void kernel_launch(void* const* d_in, const int* in_sizes, int n_in,
                              void* d_out, int out_size, void* d_ws, size_t ws_size,
                              hipStream_t stream) {
    const int*   src   = (const int*)  d_in[0];
    const float* embed = (const float*)d_in[1];
    const float* W_ih  = (const float*)d_in[2];
    const float* W_hh  = (const float*)d_in[3];
    const float* b_ih  = (const float*)d_in[4];
    const float* b_hh  = (const float*)d_in[5];
    float*     out   = (float*)d_out;
    unsigned*  bar   = (unsigned*)d_ws;                       // 16 KB counters
    _Float16*  hbase = (_Float16*)((char*)d_ws + 16384);      // 4 x 64 KB h bufs

    // counters must start at 0 every launch (ws re-poisoned to 0xAA);
    // h buffers need no init: t==0 paths stage explicit zeros.
    hipMemsetAsync(d_ws, 0, 16384, stream);

    void* args[] = { (void*)&src, (void*)&embed, (void*)&W_ih, (void*)&W_hh,
                     (void*)&b_ih, (void*)&b_hh, (void*)&out, (void*)&hbase,
                     (void*)&bar };
    hipLaunchCooperativeKernel((void*)rnn_persist, dim3(256), dim3(256),
                               args, 0, stream);
}

// Round 3
// 15923.718 us; speedup vs baseline: 3.6668x; 2.2316x over previous
//
#include <hip/hip_runtime.h>

// 2-layer tanh RNN, B=64, S=2048, D=HID=512.
// Persistent cooperative kernel, pipelined layers (layer1 lags 1 step),
// one barrier per macro-step, 4 independent 64-block clusters (per batch group).
//
// Round-3 change: NO cache-flushing fences. h state is kept coherent at the
// L3/Infinity-Cache coherence point via agent-scope RELAXED atomics
// (write-through stores, L1/L2-bypass loads). __syncthreads() drains vmcnt(0)
// per wave, so all h stores are L3-visible before the barrier counter bump.
// Read-only data (src/embed/weights) uses normal cached loads and is never
// invalidated.

#define SEQ 2048
#define LDSTR 1032   // padded f16 row stride: 2064 B == 16 mod 128 -> 2-way banks

typedef _Float16 half8 __attribute__((ext_vector_type(8)));
typedef float floatx4 __attribute__((ext_vector_type(4)));
typedef unsigned long long u64;

__device__ inline half8 cvt8(const float* p) {
    float4 f0 = ((const float4*)p)[0];
    float4 f1 = ((const float4*)p)[1];
    half8 h;
    h[0] = (_Float16)f0.x; h[1] = (_Float16)f0.y;
    h[2] = (_Float16)f0.z; h[3] = (_Float16)f0.w;
    h[4] = (_Float16)f1.x; h[5] = (_Float16)f1.y;
    h[6] = (_Float16)f1.z; h[7] = (_Float16)f1.w;
    return h;
}

// coherent (agent-scope, relaxed) 8-byte h-state access: bypasses L1/L2,
// served at the coherence point. No fence instructions generated.
__device__ inline u64 hload8(const u64* p) {
    return __hip_atomic_load(p, __ATOMIC_RELAXED, __HIP_MEMORY_SCOPE_AGENT);
}

__global__ __launch_bounds__(256, 1)
void rnn_persist(const int* __restrict__ src, const float* __restrict__ embed,
                 const float* __restrict__ W_ih, const float* __restrict__ W_hh,
                 const float* __restrict__ b_ih, const float* __restrict__ b_hh,
                 float* __restrict__ out, _Float16* hbase, unsigned* bar)
{
    __shared__ __align__(16) _Float16 Xlds[16 * LDSTR];  // 33 KB
    __shared__ __align__(16) float    red[4 * 256];      // 4 KB partial tiles

    const int tid   = threadIdx.x;
    const int bid   = blockIdx.x;
    const int layer = bid >> 7;
    const int lid   = bid & 127;
    const int bg    = lid >> 5;          // batch group (16 rows)
    const int jg    = lid & 31;          // column group (16 cols)

    const int lane = tid & 63;
    const int kw   = tid >> 6;           // wave id = K-chunk (256 wide)
    const int q    = lane >> 4;          // MFMA quad
    const int rr   = lane & 15;          // MFMA row (A) / col (B)

    // ---- persistent weights: B-frag B[k][n], n = jg*16+rr, f16, 32 VGPRs ----
    half8 bw[8];
    {
        const int wrow = jg * 16 + rr;   // output column = weight row
        const float* Wmat = (kw < 2)
            ? (W_ih + ((size_t)layer * 512 + wrow) * 512)
            : (W_hh + ((size_t)layer * 512 + wrow) * 512);
        const int kbase = (kw & 1) * 256 + q * 8;
        #pragma unroll
        for (int u = 0; u < 8; ++u)
            bw[u] = cvt8(Wmat + kbase + u * 32);
    }

    const int frow = tid >> 4;           // finalize/staging row (0..15)
    const int fcol = tid & 15;           // finalize col / staging chunk
    const float bias = b_ih[layer * 512 + jg * 16 + fcol]
                     + b_hh[layer * 512 + jg * 16 + fcol];

    _Float16* h0buf[2] = { hbase,         hbase + 32768 };  // 64x512 f16 each
    _Float16* h1buf[2] = { hbase + 65536, hbase + 98304 };

    const half8 hzero = { (_Float16)0, (_Float16)0, (_Float16)0, (_Float16)0,
                          (_Float16)0, (_Float16)0, (_Float16)0, (_Float16)0 };

    // ---- per-cluster (bg) two-level barrier: 8 groups x 8 members ----
    const int member   = layer * 32 + jg;                 // 0..63 in cluster
    const int gcnt_idx = (bg * 8 + (member >> 3)) * 64;   // 256-B spaced
    const int mast_idx = 2048 + bg * 64;

    const int brow = bg * 16 + frow;     // global batch row for this thread

    for (int m = 0; m <= SEQ; ++m) {
        const bool active = (layer == 0) ? (m < SEQ) : (m >= 1);
        const int  t      = (layer == 0) ? m : (m - 1);

        if (active) {
            // ---- stage Xcat row (f16) into LDS: 16 threads per row ----
            _Float16* dstrow = &Xlds[frow * LDSTR];
            if (layer == 0) {
                // A-half: embedding row (read-only, normal cached loads)
                const int erow = src[brow * SEQ + t];
                const float* ebase = embed + (size_t)erow * 512;
                #pragma unroll
                for (int mm = 0; mm < 4; ++mm) {
                    const int ch = fcol + 16 * mm;
                    *(half8*)&dstrow[ch * 8] = cvt8(ebase + ch * 8);
                }
                // B-half: h0_{t-1} (coherent loads)
                if (t == 0) {
                    #pragma unroll
                    for (int mm = 0; mm < 4; ++mm)
                        *(half8*)&dstrow[512 + (fcol + 16 * mm) * 8] = hzero;
                } else {
                    const u64* hb = (const u64*)(h0buf[t & 1] + brow * 512);
                    #pragma unroll
                    for (int cc = 0; cc < 8; ++cc) {
                        const int idx = fcol + 16 * cc;     // 8-byte chunk id
                        u64 v = hload8(&hb[idx]);
                        *(u64*)&dstrow[512 + idx * 4] = v;
                    }
                }
            } else {
                // A-half: h0_t (fresh from layer 0, coherent loads)
                const u64* ha = (const u64*)(h0buf[(t + 1) & 1] + brow * 512);
                #pragma unroll
                for (int cc = 0; cc < 8; ++cc) {
                    const int idx = fcol + 16 * cc;
                    u64 v = hload8(&ha[idx]);
                    *(u64*)&dstrow[idx * 4] = v;
                }
                // B-half: h1_{t-1} (coherent loads)
                if (t == 0) {
                    #pragma unroll
                    for (int mm = 0; mm < 4; ++mm)
                        *(half8*)&dstrow[512 + (fcol + 16 * mm) * 8] = hzero;
                } else {
                    const u64* hb = (const u64*)(h1buf[t & 1] + brow * 512);
                    #pragma unroll
                    for (int cc = 0; cc < 8; ++cc) {
                        const int idx = fcol + 16 * cc;
                        u64 v = hload8(&hb[idx]);
                        *(u64*)&dstrow[512 + idx * 4] = v;
                    }
                }
            }
            __syncthreads();

            // ---- MFMA: A[m=rr][k] from LDS, B from registers, K=256/wave ----
            floatx4 acc = { 0.f, 0.f, 0.f, 0.f };
            const _Float16* arow = &Xlds[rr * LDSTR + kw * 256 + q * 8];
            #pragma unroll
            for (int u = 0; u < 8; ++u) {
                half8 a = *(const half8*)&arow[u * 32];
                acc = __builtin_amdgcn_mfma_f32_16x16x32_f16(a, bw[u], acc, 0, 0, 0);
            }
            // partial tile -> LDS: red[kw][row=q*4+reg][col=rr]
            #pragma unroll
            for (int reg = 0; reg < 4; ++reg)
                red[kw * 256 + (q * 4 + reg) * 16 + rr] = acc[reg];
            __syncthreads();

            // ---- finalize element (frow, fcol): K-reduce + bias + tanh ----
            float z = red[tid] + red[256 + tid] + red[512 + tid] + red[768 + tid]
                    + bias;
            float h = tanhf(z);
            const int jcol = jg * 16 + fcol;
            _Float16* hw = (layer == 0) ? h0buf[(t + 1) & 1] : h1buf[(t + 1) & 1];
            // coherent write-through store (2 B)
            union { _Float16 f; unsigned short u; } cv; cv.f = (_Float16)h;
            __hip_atomic_store((unsigned short*)&hw[brow * 512 + jcol], cv.u,
                               __ATOMIC_RELAXED, __HIP_MEMORY_SCOPE_AGENT);
            if (t == SEQ - 1)
                out[layer * (64 * 512) + brow * 512 + jcol] = h;
        }

        // ---- cluster barrier: pure relaxed atomics, no cache maintenance ----
        // __syncthreads drains vmcnt(0) for every wave -> all write-through h
        // stores are visible at the coherence point before tid0 proceeds.
        __syncthreads();
        if (tid == 0) {
            __builtin_amdgcn_s_waitcnt(0);              // belt & suspenders
            __atomic_signal_fence(__ATOMIC_SEQ_CST);    // compiler-only
            unsigned old = __hip_atomic_fetch_add(&bar[gcnt_idx], 1u,
                              __ATOMIC_RELAXED, __HIP_MEMORY_SCOPE_AGENT);
            if (old == (unsigned)(8 * (m + 1) - 1))
                __hip_atomic_fetch_add(&bar[mast_idx], 1u,
                              __ATOMIC_RELAXED, __HIP_MEMORY_SCOPE_AGENT);
            while (__hip_atomic_load(&bar[mast_idx], __ATOMIC_RELAXED,
                              __HIP_MEMORY_SCOPE_AGENT) < (unsigned)(8 * (m + 1)))
                __builtin_amdgcn_s_sleep(1);
            __atomic_signal_fence(__ATOMIC_SEQ_CST);    // compiler-only
        }
        __syncthreads();
    }
}

extern "C" void kernel_launch(void* const* d_in, const int* in_sizes, int n_in,
                              void* d_out, int out_size, void* d_ws, size_t ws_size,
                              hipStream_t stream) {
    const int*   src   = (const int*)  d_in[0];
    const float* embed = (const float*)d_in[1];
    const float* W_ih  = (const float*)d_in[2];
    const float* W_hh  = (const float*)d_in[3];
    const float* b_ih  = (const float*)d_in[4];
    const float* b_hh  = (const float*)d_in[5];
    float*     out   = (float*)d_out;
    unsigned*  bar   = (unsigned*)d_ws;                       // 16 KB counters
    _Float16*  hbase = (_Float16*)((char*)d_ws + 16384);      // 4 x 64 KB h bufs

    // counters must start at 0 every launch (ws re-poisoned to 0xAA);
    // h buffers need no init: t==0 paths stage explicit zeros.
    hipMemsetAsync(d_ws, 0, 16384, stream);

    void* args[] = { (void*)&src, (void*)&embed, (void*)&W_ih, (void*)&W_hh,
                     (void*)&b_ih, (void*)&b_hh, (void*)&out, (void*)&hbase,
                     (void*)&bar };
    hipLaunchCooperativeKernel((void*)rnn_persist, dim3(256), dim3(256),
                               args, 0, stream);
}

// Round 7
// 15581.165 us; speedup vs baseline: 3.7474x; 1.0220x over previous
//
#include <hip/hip_runtime.h>

// 2-layer tanh RNN, B=64, S=2048, D=HID=512.
// Round 7: identical body to round 6 (wave-autonomous flag-sync design), but
// launched with a PLAIN <<<256,256>>> instead of hipLaunchCooperativeKernel.
// Evidence: r4/r5/r6 all show the never-launched signature while r1-r3 (same
// geometry, 52-VGPR kernels) launched fine -> the cooperative validator is
// rejecting the high-VGPR kernel image. We don't need the cooperative API:
// sync is custom flag-based; co-residency follows from grid=256=#CUs with
// __launch_bounds__(256,1) (>=1 block/CU by construction) on an idle device.
//
// Wave 0 of block g owns tile (L = g>>7, bg = (g>>5)&3, jg = g&31): 16 batch
// rows x 16 cols, full K=1024, weights register-resident (128 VGPRs). Waves
// 1..3 exit. No LDS, no __syncthreads.
// Sync: producer stores h tile straight from MFMA C/D layout (4 x 2B
// agent-scope stores), s_waitcnt 0, stamps flag = t+1; consumers poll the 64
// flags of their batch group with a 64-lane bypass load + ballot.
// h buffers 4-deep; layer-0 back-pressures on stamp_1 >= t-3 (WAR-safe).
// Polls carry a 64M-iteration escape hatch: converts any protocol bug into a
// bounded wrong-answer (diagnosable) instead of a hang.

#define SEQ 2048

typedef _Float16 half8 __attribute__((ext_vector_type(8)));
typedef float floatx4 __attribute__((ext_vector_type(4)));
typedef unsigned long long u64;

__device__ inline half8 cvt8(const float* p) {
    float4 f0 = ((const float4*)p)[0];
    float4 f1 = ((const float4*)p)[1];
    half8 h;
    h[0]=(_Float16)f0.x; h[1]=(_Float16)f0.y; h[2]=(_Float16)f0.z; h[3]=(_Float16)f0.w;
    h[4]=(_Float16)f1.x; h[5]=(_Float16)f1.y; h[6]=(_Float16)f1.z; h[7]=(_Float16)f1.w;
    return h;
}

__device__ inline u64 ld8(const void* p) {
    return __hip_atomic_load((const u64*)p, __ATOMIC_RELAXED, __HIP_MEMORY_SCOPE_AGENT);
}
__device__ inline half8 ldfrag(const _Float16* p) {   // 16 B coherent load
    union { u64 d[2]; half8 h; } u;
    u.d[0] = ld8(p);
    u.d[1] = ld8(p + 4);
    return u.h;
}

#define MFMA(a, b, c) __builtin_amdgcn_mfma_f32_16x16x32_f16((a), (b), (c), 0, 0, 0)

__global__ __launch_bounds__(256, 1)
void rnn_persist(const int* __restrict__ src, const float* __restrict__ embed,
                 const float* __restrict__ W_ih, const float* __restrict__ W_hh,
                 const float* __restrict__ b_ih, const float* __restrict__ b_hh,
                 float* __restrict__ out, _Float16* hbase, int* flags)
{
    const int tid = threadIdx.x;
    if (tid >= 64) return;               // wave 0 only; no LDS / __syncthreads

    const int lane = tid;
    const int g    = blockIdx.x;         // tile id 0..255
    const int L    = g >> 7;
    const int bg   = (g >> 5) & 3;
    const int jg   = g & 31;
    const int q    = lane >> 4;
    const int rr   = lane & 15;
    const int col  = jg * 16 + rr;

    _Float16* h0s = hbase;                         // 4 slots of 64x512 f16
    _Float16* h1s = hbase + 4 * 64 * 512;          // 4 slots of 64x512 f16

    // ---- persistent weights: 16 cols x K=1024, f16, 128 VGPRs ----
    half8 bw[32];
    {
        const float* Wi = W_ih + ((size_t)L * 512 + col) * 512;
        const float* Wh = W_hh + ((size_t)L * 512 + col) * 512;
        #pragma unroll
        for (int u = 0; u < 16; ++u) bw[u]      = cvt8(Wi + u * 32 + q * 8);
        #pragma unroll
        for (int u = 0; u < 16; ++u) bw[16 + u] = cvt8(Wh + u * 32 + q * 8);
    }
    const float bias = b_ih[L * 512 + col] + b_hh[L * 512 + col];

    const int arow = bg * 16 + rr;       // batch row whose A-frags this lane loads
    int* flg = flags + bg * 64;          // [layer(2)][jg(32)] stamps for this bg
    const int lf = lane >> 5;            // which layer's flag this lane polls

    for (int t = 0; t < SEQ; ++t) {
        floatx4 acc0 = {0.f,0.f,0.f,0.f}, acc1 = {0.f,0.f,0.f,0.f};

        if (L == 0) {
            // ---- x-part: embed row (cached loads), BEFORE the poll ----
            const int erow = src[arow * SEQ + t];
            const float* eb = embed + (size_t)erow * 512 + q * 8;
            half8 ax[16];
            #pragma unroll
            for (int u = 0; u < 16; ++u) ax[u] = cvt8(eb + u * 32);
            #pragma unroll
            for (int u = 0; u < 16; ++u) {
                if (u & 1) acc1 = MFMA(ax[u], bw[u], acc1);
                else       acc0 = MFMA(ax[u], bw[u], acc0);
            }
            // ---- wait: h0 peers done step t-1; layer-1 past t-4 (WAR) ----
            const int tgt = (lf == 0) ? t : (t - 3);
            for (long it = 0; it < (1L << 26); ++it) {
                int v = __hip_atomic_load(&flg[lane], __ATOMIC_RELAXED,
                                          __HIP_MEMORY_SCOPE_AGENT);
                if (__ballot(v >= tgt) == ~0ull) break;
                __builtin_amdgcn_s_sleep(1);
            }
            __atomic_signal_fence(__ATOMIC_SEQ_CST);
            // ---- h-part: h0_{t-1} ----
            if (t > 0) {
                const _Float16* hb = h0s + ((t - 1) & 3) * (64 * 512)
                                   + arow * 512 + q * 8;
                half8 ah[16];
                #pragma unroll
                for (int u = 0; u < 16; ++u) ah[u] = ldfrag(hb + u * 32);
                #pragma unroll
                for (int u = 0; u < 16; ++u) {
                    if (u & 1) acc1 = MFMA(ah[u], bw[16 + u], acc1);
                    else       acc0 = MFMA(ah[u], bw[16 + u], acc0);
                }
            }
        } else {
            // ---- wait: h0_t ready (stamp_0 >= t+1); h1 peers done t-1 ----
            const int tgt = (lf == 0) ? (t + 1) : t;
            for (long it = 0; it < (1L << 26); ++it) {
                int v = __hip_atomic_load(&flg[lane], __ATOMIC_RELAXED,
                                          __HIP_MEMORY_SCOPE_AGENT);
                if (__ballot(v >= tgt) == ~0ull) break;
                __builtin_amdgcn_s_sleep(1);
            }
            __atomic_signal_fence(__ATOMIC_SEQ_CST);
            // ---- x-part: h0_t ----
            {
                const _Float16* xa = h0s + (t & 3) * (64 * 512)
                                   + arow * 512 + q * 8;
                half8 ax[16];
                #pragma unroll
                for (int u = 0; u < 16; ++u) ax[u] = ldfrag(xa + u * 32);
                #pragma unroll
                for (int u = 0; u < 16; ++u) {
                    if (u & 1) acc1 = MFMA(ax[u], bw[u], acc1);
                    else       acc0 = MFMA(ax[u], bw[u], acc0);
                }
            }
            // ---- h-part: h1_{t-1} ----
            if (t > 0) {
                const _Float16* hb = h1s + ((t - 1) & 3) * (64 * 512)
                                   + arow * 512 + q * 8;
                half8 ah[16];
                #pragma unroll
                for (int u = 0; u < 16; ++u) ah[u] = ldfrag(hb + u * 32);
                #pragma unroll
                for (int u = 0; u < 16; ++u) {
                    if (u & 1) acc1 = MFMA(ah[u], bw[16 + u], acc1);
                    else       acc0 = MFMA(ah[u], bw[16 + u], acc0);
                }
            }
        }

        // ---- finalize: bias + tanh; C/D layout row=q*4+r, col=rr ----
        float hv[4];
        #pragma unroll
        for (int r = 0; r < 4; ++r)
            hv[r] = tanhf(acc0[r] + acc1[r] + bias);

        if (t == SEQ - 1) {
            #pragma unroll
            for (int r = 0; r < 4; ++r)
                out[(size_t)L * 64 * 512 + (size_t)(bg * 16 + q * 4 + r) * 512 + col]
                    = hv[r];
        }

        // ---- h store: straight from C/D layout, 4 x 2B coherent stores ----
        {
            _Float16* hw = ((L == 0) ? h0s : h1s) + (t & 3) * (64 * 512)
                         + (size_t)(bg * 16) * 512 + col;
            #pragma unroll
            for (int r = 0; r < 4; ++r) {
                union { _Float16 f; unsigned short u; } cv;
                cv.f = (_Float16)hv[r];
                __hip_atomic_store((unsigned short*)(hw + (q * 4 + r) * 512),
                                   cv.u, __ATOMIC_RELAXED,
                                   __HIP_MEMORY_SCOPE_AGENT);
            }
        }
        __atomic_signal_fence(__ATOMIC_SEQ_CST);
        __builtin_amdgcn_s_waitcnt(0);      // whole wave's h stores at L3
        __atomic_signal_fence(__ATOMIC_SEQ_CST);
        if (lane == 0)
            __hip_atomic_store(&flg[L * 32 + jg], t + 1, __ATOMIC_RELAXED,
                               __HIP_MEMORY_SCOPE_AGENT);
    }
}

extern "C" void kernel_launch(void* const* d_in, const int* in_sizes, int n_in,
                              void* d_out, int out_size, void* d_ws, size_t ws_size,
                              hipStream_t stream) {
    const int*   src   = (const int*)  d_in[0];
    const float* embed = (const float*)d_in[1];
    const float* W_ih  = (const float*)d_in[2];
    const float* W_hh  = (const float*)d_in[3];
    const float* b_ih  = (const float*)d_in[4];
    const float* b_hh  = (const float*)d_in[5];
    float*     out   = (float*)d_out;
    int*       flags = (int*)d_ws;                            // [4 bg][2][32]
    _Float16*  hbase = (_Float16*)((char*)d_ws + 16384);      // 8 slots 64x512

    // flags must start at 0 (ws re-poisoned to 0xAA each timed launch);
    // h slots need no init: t==0 skips all h-slot reads.
    hipMemsetAsync(d_ws, 0, 16384, stream);

    // Plain launch: co-residency by capacity (grid = 256 = #CUs, >=1 block/CU
    // by __launch_bounds__), no cooperative-API validation in the path.
    rnn_persist<<<dim3(256), dim3(256), 0, stream>>>(
        src, embed, W_ih, W_hh, b_ih, b_hh, out, hbase, flags);
}